// Round 1
// baseline (2617.853 us; speedup 1.0000x reference)
//
#include <hip/hip_runtime.h>

#define NSEQ 1920
#define NTOK 72
#define DIM 256
#define NHEAD 8
#define HD 32
#define TOPM 20

typedef __attribute__((ext_vector_type(8))) short s8v;
typedef __attribute__((ext_vector_type(4))) float f4v;

#define MFMA16(a, b, c) __builtin_amdgcn_mfma_f32_16x16x32_bf16((a), (b), (c), 0, 0, 0)

__device__ __forceinline__ unsigned short f2bf(float f) {
  unsigned int u = __float_as_uint(f);
  unsigned int r = (u + 0x7FFFu + ((u >> 16) & 1u)) >> 16;
  return (unsigned short)r;
}
__device__ __forceinline__ float bf2f(unsigned short s) {
  return __uint_as_float(((unsigned int)s) << 16);
}

// ---------------- weight pack kernel (runs every launch; ~1 MB ws) ----------
// wq: [L][H][j=96][k=256] bf16   (j: 0-31 q, 32-63 k, 64-95 v; col-major-in-k
//     so B-fragments are contiguous 16B chunks)
// wp: [L][H][n=256][k=32] bf16
__global__ void pack_w(const float* __restrict__ qkv_w, const float* __restrict__ proj_w,
                       unsigned short* __restrict__ wq, unsigned short* __restrict__ wp) {
  int idx = blockIdx.x * 256 + threadIdx.x;
  if (idx < 2 * 8 * 96 * 256) {
    int k = idx & 255; int rest = idx >> 8; int j = rest % 96; int lh = rest / 96;
    int h = lh & 7, l = lh >> 3;
    int which = j >> 5, d = j & 31;
    wq[idx] = f2bf(qkv_w[(l * 256 + k) * 768 + which * 256 + h * 32 + d]);
  }
  if (idx < 2 * 8 * 256 * 32) {
    int k = idx & 31; int rest = idx >> 5; int n = rest & 255; int lh = rest >> 8;
    int h = lh & 7, l = lh >> 3;
    wp[idx] = f2bf(proj_w[(l * 256 + h * 32 + k) * 256 + n]);
  }
}

// ---------------- LDS layout (bytes) ----------------------------------------
#define XS_S 264   // xs  [80][264] bf16  (stride pad: 2-way max bank alias)
#define WB_S 264   // wb  [96][264] bf16  (unioned with sc)
#define QS_S 40    // qs/ks [80][40] bf16
#define VT_S 104   // vt  [32][104] bf16  (v transposed; cols 80..103 stay 0)
#define SC_S 81    // sc  [80][81]  f32   (union with wb)
#define PS_S 104   // ps  [80][104] bf16  (pad rows/cols stay 0)
#define OH_S 40    // oh  [80][40]  bf16

#define OFF_XS 0
#define SZ_XS (80 * 264 * 2)              // 42240
#define OFF_WB (OFF_XS + SZ_XS)           // 42240
#define SZ_WB (96 * 264 * 2)              // 50688 (>= sc 25920)
#define OFF_QS (OFF_WB + SZ_WB)           // 92928
#define OFF_KS (OFF_QS + 80 * 40 * 2)     // 99328
#define OFF_VT (OFF_KS + 80 * 40 * 2)     // 105728
#define OFF_PS (OFF_VT + 32 * 104 * 2)    // 112384
#define OFF_OH (OFF_PS + 80 * 104 * 2)    // 129024
#define SMEM_BYTES (OFF_OH + 80 * 40 * 2) // 135424

__global__ __launch_bounds__(512, 2)
void fused_kernel(const float* __restrict__ rf, const float* __restrict__ pos,
                  const float* __restrict__ qkv_b, const float* __restrict__ proj_b,
                  const float* __restrict__ ln_g, const float* __restrict__ ln_b,
                  const float* __restrict__ w1, const float* __restrict__ b1,
                  const float* __restrict__ w2, const float* __restrict__ b2,
                  const unsigned short* __restrict__ wq, const unsigned short* __restrict__ wp,
                  float* __restrict__ out)
{
  __shared__ __align__(16) char smem[SMEM_BYTES];
  __shared__ float red[160];
  __shared__ float mbuf[256];
  __shared__ float hbuf[128];

  unsigned short* xs = (unsigned short*)(smem + OFF_XS);
  unsigned short* wb = (unsigned short*)(smem + OFF_WB);
  float*          sc = (float*)(smem + OFF_WB);
  unsigned short* qs = (unsigned short*)(smem + OFF_QS);
  unsigned short* ks = (unsigned short*)(smem + OFF_KS);
  unsigned short* vt = (unsigned short*)(smem + OFF_VT);
  unsigned short* ps = (unsigned short*)(smem + OFF_PS);
  unsigned short* oh = (unsigned short*)(smem + OFF_OH);

  const int tid = threadIdx.x;
  const int w   = tid >> 6;     // wave 0..7
  const int l   = tid & 63;     // lane
  const int q4  = l >> 4;       // quad 0..3
  const int l15 = l & 15;
  const int b   = blockIdx.x;

  // zero xs (incl pad rows/cols), ps, vt once; rewritten regions are overwritten later
  { unsigned int* p = (unsigned int*)xs; for (int i = tid; i < SZ_XS / 4; i += 512) p[i] = 0u; }
  { unsigned int* p = (unsigned int*)ps; for (int i = tid; i < (80 * 104 * 2) / 4; i += 512) p[i] = 0u; }
  { unsigned int* p = (unsigned int*)vt; for (int i = tid; i < (32 * 104 * 2) / 4; i += 512) p[i] = 0u; }
  __syncthreads();

  // x = rf[b]^T + pos   (rf[b][c][n] layout -> contiguous in n)
  const float* rfb = rf + (long)b * (DIM * NTOK);
  for (int i = tid; i < DIM * NTOK; i += 512) {
    int c = i / NTOK, n = i - c * NTOK;
    xs[n * XS_S + c] = f2bf(rfb[i] + pos[n * DIM + c]);
  }
  __syncthreads();

  const int c0 = w * 32 + l15, c1 = c0 + 16;   // this wave's output columns

  for (int li = 0; li < 2; ++li) {
    const unsigned short* wqL = wq + (long)li * 8 * 96 * 256;
    const unsigned short* wpL = wp + (long)li * 8 * 256 * 32;
    const float* qbL = qkv_b + li * 768;

    // persistent proj-output accumulators: wave w owns cols [32w, 32w+32), rows via mt
    f4v yacc[5][2];
    {
      float pb0 = proj_b[li * 256 + c0], pb1 = proj_b[li * 256 + c1];
      #pragma unroll
      for (int mt = 0; mt < 5; ++mt) {
        yacc[mt][0] = (f4v){pb0, pb0, pb0, pb0};
        yacc[mt][1] = (f4v){pb1, pb1, pb1, pb1};
      }
    }

    for (int h = 0; h < 8; ++h) {
      // ---- stage W slice for this head (96x256 bf16, b128 copies) ----
      const unsigned short* wqh = wqL + h * 96 * 256;
      for (int i = tid; i < 96 * 32; i += 512) {
        int j = i >> 5, k8 = (i & 31) << 3;
        *(s8v*)(wb + j * WB_S + k8) = *(const s8v*)(wqh + j * 256 + k8);
      }
      __syncthreads();

      // ---- qkv GEMM: waves 0..2, mt-pairs {0,1},{2,3},{4} x 6 nt ----
      if (w < 3) {
        const int mt0 = w * 2;
        const int nmt = (w == 2) ? 1 : 2;
        f4v acc[2][6];
        #pragma unroll
        for (int a = 0; a < 2; ++a)
          #pragma unroll
          for (int nt = 0; nt < 6; ++nt) acc[a][nt] = (f4v){0, 0, 0, 0};
        for (int kk = 0; kk < 8; ++kk) {
          int k0 = kk * 32 + q4 * 8;
          s8v a0 = *(const s8v*)(xs + (mt0 * 16 + l15) * XS_S + k0);
          s8v a1 = (nmt > 1) ? *(const s8v*)(xs + ((mt0 + 1) * 16 + l15) * XS_S + k0) : a0;
          #pragma unroll
          for (int nt = 0; nt < 6; ++nt) {
            s8v bf = *(const s8v*)(wb + (nt * 16 + l15) * WB_S + k0);
            acc[0][nt] = MFMA16(a0, bf, acc[0][nt]);
            if (nmt > 1) acc[1][nt] = MFMA16(a1, bf, acc[1][nt]);
          }
        }
        #pragma unroll
        for (int mi = 0; mi < 2; ++mi) {
          if (mi < nmt) {
            #pragma unroll
            for (int nt = 0; nt < 6; ++nt) {
              int col = nt * 16 + l15;
              int which = col >> 5, d = col & 31;
              float bv = qbL[which * 256 + h * 32 + d];
              int rowb = (mt0 + mi) * 16 + q4 * 4;
              #pragma unroll
              for (int r = 0; r < 4; ++r) {
                unsigned short v = f2bf(acc[mi][nt][r] + bv);
                int row = rowb + r;
                if (which == 0)      qs[row * QS_S + d] = v;
                else if (which == 1) ks[row * QS_S + d] = v;
                else                 vt[d * VT_S + row] = v;   // v stored transposed
              }
            }
          }
        }
      }
      __syncthreads();

      // ---- scores = q k^T * scale  (25 tiles, K=32 in one MFMA) ----
      for (int t = w; t < 25; t += 8) {
        int mt = t / 5, kt = t - mt * 5;
        s8v a   = *(const s8v*)(qs + (mt * 16 + l15) * QS_S + q4 * 8);
        s8v bfr = *(const s8v*)(ks + (kt * 16 + l15) * QS_S + q4 * 8);
        f4v c = MFMA16(a, bfr, ((f4v){0, 0, 0, 0}));
        int rowb = mt * 16 + q4 * 4, col = kt * 16 + l15;
        #pragma unroll
        for (int r = 0; r < 4; ++r) sc[(rowb + r) * SC_S + col] = c[r] * 0.17677669529663687f;
      }
      __syncthreads();

      // ---- exact top-20 threshold (bit-greedy radix) + softmax, 8 lanes/row ----
      for (int rbase = 0; rbase < 80; rbase += 64) {
        int row = rbase + w * 8 + (l >> 3);
        if (row < NTOK) {
          int sub = l & 7;                       // 8 lanes x 9 vals = 72 exactly
          float vf[9]; unsigned int uv[9];
          #pragma unroll
          for (int i = 0; i < 9; ++i) {
            float v = sc[row * SC_S + sub * 9 + i];
            vf[i] = v;
            unsigned int s = __float_as_uint(v);
            uv[i] = s ^ (unsigned int)(((int)s >> 31) | 0x80000000);
          }
          unsigned int thr = 0u;                 // max c with count(u>=c) >= 20  == 20th largest
          for (int bit = 31; bit >= 0; --bit) {
            unsigned int cand = thr | (1u << bit);
            int cnt = 0;
            #pragma unroll
            for (int i = 0; i < 9; ++i) cnt += (uv[i] >= cand) ? 1 : 0;
            cnt += __shfl_xor(cnt, 1);
            cnt += __shfl_xor(cnt, 2);
            cnt += __shfl_xor(cnt, 4);
            if (cnt >= TOPM) thr = cand;
          }
          float mx = vf[0];
          #pragma unroll
          for (int i = 1; i < 9; ++i) mx = fmaxf(mx, vf[i]);
          mx = fmaxf(mx, __shfl_xor(mx, 1));
          mx = fmaxf(mx, __shfl_xor(mx, 2));
          mx = fmaxf(mx, __shfl_xor(mx, 4));
          float ssum = 0.f;
          #pragma unroll
          for (int i = 0; i < 9; ++i) {
            float e = (uv[i] >= thr) ? __expf(vf[i] - mx) : 0.f;
            vf[i] = e; ssum += e;
          }
          ssum += __shfl_xor(ssum, 1);
          ssum += __shfl_xor(ssum, 2);
          ssum += __shfl_xor(ssum, 4);
          float inv = 1.f / ssum;
          #pragma unroll
          for (int i = 0; i < 9; ++i) ps[row * PS_S + sub * 9 + i] = f2bf(vf[i] * inv);
        }
      }
      __syncthreads();

      // ---- out_h = P V  (10 tiles, K=96: ps/vt pads are zero) ----
      for (int t = w; t < 10; t += 8) {
        int mt = t >> 1, dt = t & 1;
        f4v acc = (f4v){0, 0, 0, 0};
        #pragma unroll
        for (int kk = 0; kk < 3; ++kk) {
          int k0 = kk * 32 + q4 * 8;
          s8v a   = *(const s8v*)(ps + (mt * 16 + l15) * PS_S + k0);
          s8v bfr = *(const s8v*)(vt + (dt * 16 + l15) * VT_S + k0);
          acc = MFMA16(a, bfr, acc);
        }
        int rowb = mt * 16 + q4 * 4, d = dt * 16 + l15;
        #pragma unroll
        for (int r = 0; r < 4; ++r) oh[(rowb + r) * OH_S + d] = f2bf(acc[r]);
      }
      __syncthreads();

      // ---- proj: accumulate out_h @ proj[h-slice] into yacc regs ----
      {
        const unsigned short* wph = wpL + h * 256 * 32;
        s8v b0 = *(const s8v*)(wph + c0 * 32 + q4 * 8);
        s8v b1 = *(const s8v*)(wph + c1 * 32 + q4 * 8);
        #pragma unroll
        for (int mt = 0; mt < 5; ++mt) {
          s8v a = *(const s8v*)(oh + (mt * 16 + l15) * OH_S + q4 * 8);
          yacc[mt][0] = MFMA16(a, b0, yacc[mt][0]);
          yacc[mt][1] = MFMA16(a, b1, yacc[mt][1]);
        }
      }
      __syncthreads();
    } // heads

    // ---- residual + LayerNorm (fp32 stats via shuffle + LDS atomics) ----
    if (tid < 160) red[tid] = 0.f;
    __syncthreads();
    #pragma unroll
    for (int mt = 0; mt < 5; ++mt) {
      #pragma unroll
      for (int r = 0; r < 4; ++r) {
        int row = mt * 16 + q4 * 4 + r;
        float z0 = bf2f(xs[row * XS_S + c0]) + yacc[mt][0][r];
        float z1 = bf2f(xs[row * XS_S + c1]) + yacc[mt][1][r];
        yacc[mt][0][r] = z0; yacc[mt][1][r] = z1;
        float s1 = z0 + z1, s2 = z0 * z0 + z1 * z1;
        s1 += __shfl_xor(s1, 1); s2 += __shfl_xor(s2, 1);
        s1 += __shfl_xor(s1, 2); s2 += __shfl_xor(s2, 2);
        s1 += __shfl_xor(s1, 4); s2 += __shfl_xor(s2, 4);
        s1 += __shfl_xor(s1, 8); s2 += __shfl_xor(s2, 8);
        if (l15 == 0) { atomicAdd(&red[row * 2], s1); atomicAdd(&red[row * 2 + 1], s2); }
      }
    }
    __syncthreads();
    {
      float g0 = ln_g[li * 256 + c0], g1 = ln_g[li * 256 + c1];
      float be0 = ln_b[li * 256 + c0], be1 = ln_b[li * 256 + c1];
      #pragma unroll
      for (int mt = 0; mt < 5; ++mt) {
        #pragma unroll
        for (int r = 0; r < 4; ++r) {
          int row = mt * 16 + q4 * 4 + r;
          float mu = red[row * 2] * (1.f / 256.f);
          float var = red[row * 2 + 1] * (1.f / 256.f) - mu * mu;
          float rstd = rsqrtf(var + 1e-5f);
          float o0 = (yacc[mt][0][r] - mu) * rstd * g0 + be0;
          float o1 = (yacc[mt][1][r] - mu) * rstd * g1 + be1;
          bool live = row < NTOK;
          xs[row * XS_S + c0] = f2bf(live ? o0 : 0.f);
          xs[row * XS_S + c1] = f2bf(live ? o1 : 0.f);
        }
      }
    }
    __syncthreads();
  } // layers

  // ---- mean over tokens + 2-layer MLP classifier ----
  if (tid < 256) {
    float s = 0.f;
    for (int n = 0; n < NTOK; ++n) s += bf2f(xs[n * XS_S + tid]);
    mbuf[tid] = s * (1.f / 72.f);
  }
  __syncthreads();
  if (tid < 128) {
    float s = b1[tid];
    for (int k = 0; k < 256; ++k) s += mbuf[k] * w1[k * 128 + tid];
    hbuf[tid] = fmaxf(s, 0.f);
  }
  __syncthreads();
  if (w == 0) {
    float p = hbuf[l] * w2[l] + hbuf[l + 64] * w2[l + 64];
    p += __shfl_xor(p, 1);  p += __shfl_xor(p, 2);  p += __shfl_xor(p, 4);
    p += __shfl_xor(p, 8);  p += __shfl_xor(p, 16); p += __shfl_xor(p, 32);
    if (l == 0) out[b] = p + b2[0];
  }
}

extern "C" void kernel_launch(void* const* d_in, const int* in_sizes, int n_in,
                              void* d_out, int out_size, void* d_ws, size_t ws_size,
                              hipStream_t stream) {
  const float* rf    = (const float*)d_in[0];
  const float* pos   = (const float*)d_in[1];
  const float* qkvw  = (const float*)d_in[2];
  const float* qkvb  = (const float*)d_in[3];
  const float* projw = (const float*)d_in[4];
  const float* projb = (const float*)d_in[5];
  const float* lng   = (const float*)d_in[6];
  const float* lnb   = (const float*)d_in[7];
  const float* w1    = (const float*)d_in[8];
  const float* b1    = (const float*)d_in[9];
  const float* w2    = (const float*)d_in[10];
  const float* b2    = (const float*)d_in[11];
  float* out = (float*)d_out;

  unsigned short* wq = (unsigned short*)d_ws;            // 393216 bf16
  unsigned short* wp = wq + 2 * 8 * 96 * 256;            // 131072 bf16  (total ~1 MB)

  hipLaunchKernelGGL(pack_w, dim3(1536), dim3(256), 0, stream, qkvw, projw, wq, wp);
  hipLaunchKernelGGL(fused_kernel, dim3(NSEQ), dim3(512), 0, stream,
                     rf, pos, qkvb, projb, lng, lnb, w1, b1, w2, b2, wq, wp, out);
}

// Round 2
// 2049.224 us; speedup vs baseline: 1.2775x; 1.2775x over previous
//
#include <hip/hip_runtime.h>

#define NTOK 72
#define TOPM 20

typedef __attribute__((ext_vector_type(8))) short s8v;
typedef __attribute__((ext_vector_type(4))) float f4v;

#define MFMA16(a, b, c) __builtin_amdgcn_mfma_f32_16x16x32_bf16((a), (b), (c), 0, 0, 0)

__device__ __forceinline__ unsigned short f2bf(float f) {
  unsigned int u = __float_as_uint(f);
  unsigned int r = (u + 0x7FFFu + ((u >> 16) & 1u)) >> 16;
  return (unsigned short)r;
}
__device__ __forceinline__ float bf2f(unsigned short s) {
  return __uint_as_float(((unsigned int)s) << 16);
}

// ---------------- weight pack --------------------------------------------
// wq: [L][768][256] bf16 where row j768 = h*96 + which*32 + d  (k contiguous)
// wp: [L][256][256] bf16 where row n, col k  (k contiguous)
__global__ void pack_w(const float* __restrict__ qkv_w, const float* __restrict__ proj_w,
                       unsigned short* __restrict__ wq, unsigned short* __restrict__ wp) {
  int idx = blockIdx.x * 256 + threadIdx.x;
  if (idx < 2 * 768 * 256) {
    int k = idx & 255; int rest = idx >> 8; int j = rest % 768; int l = rest / 768;
    int h = j / 96, j96 = j - h * 96;
    int which = j96 >> 5, d = j96 & 31;
    wq[idx] = f2bf(qkv_w[(l * 256 + k) * 768 + which * 256 + h * 32 + d]);
  }
  if (idx < 2 * 256 * 256) {
    int k = idx & 255, n = (idx >> 8) & 255, l = idx >> 16;
    wp[idx] = f2bf(proj_w[(l * 256 + k) * 256 + n]);
  }
}

// ---------------- K2: qkv GEMM per sequence ------------------------------
// qkvbuf chunk layout: [(b-b0)][h][which][72][32] bf16
__global__ __launch_bounds__(512, 4)
void k_qkv(const float* __restrict__ rf, const float* __restrict__ pos,
           unsigned short* __restrict__ xb,
           const unsigned short* __restrict__ wq,
           const float* __restrict__ qkv_b,
           unsigned short* __restrict__ qkvbuf,
           int layer, int b0)
{
  __shared__ __align__(16) unsigned short xs[80 * 264];
  const int tid = threadIdx.x, w = tid >> 6, l = tid & 63, q4 = l >> 4, l15 = l & 15;
  const int b = blockIdx.x + b0;

  for (int i = tid; i < 80 * 264 / 2; i += 512) ((unsigned int*)xs)[i] = 0u;
  __syncthreads();
  if (layer == 0) {
    const float* rfb = rf + (size_t)b * 18432;
    for (int i = tid; i < 18432; i += 512) {
      int c = i / 72, n = i - c * 72;
      xs[n * 264 + c] = f2bf(rfb[i] + pos[n * 256 + c]);
    }
  } else {
    const unsigned short* xbb = xb + (size_t)b * 18432;
    for (int i = tid; i < 2304; i += 512) {
      int n = i >> 5, c8 = (i & 31) << 3;
      *(s8v*)(xs + n * 264 + c8) = *(const s8v*)(xbb + n * 256 + c8);
    }
  }
  __syncthreads();
  if (layer == 0) {  // persist x for the residual path
    unsigned short* xbb = xb + (size_t)b * 18432;
    for (int i = tid; i < 2304; i += 512) {
      int n = i >> 5, c8 = (i & 31) << 3;
      *(s8v*)(xbb + n * 256 + c8) = *(const s8v*)(xs + n * 264 + c8);
    }
  }

  const unsigned short* wqB = wq + (size_t)layer * 768 * 256;
  for (int pass = 0; pass < 3; ++pass) {
    f4v acc[2][5];
    #pragma unroll
    for (int j = 0; j < 2; ++j)
      #pragma unroll
      for (int mt = 0; mt < 5; ++mt) acc[j][mt] = (f4v){0, 0, 0, 0};
    for (int kk = 0; kk < 8; ++kk) {
      int k0 = kk * 32 + q4 * 8;
      s8v a[5];
      #pragma unroll
      for (int mt = 0; mt < 5; ++mt) a[mt] = *(const s8v*)(xs + (mt * 16 + l15) * 264 + k0);
      #pragma unroll
      for (int j = 0; j < 2; ++j) {
        int jrow = (w + 8 * (pass * 2 + j)) * 16 + l15;
        s8v bf = *(const s8v*)(wqB + jrow * 256 + k0);
        #pragma unroll
        for (int mt = 0; mt < 5; ++mt) acc[j][mt] = MFMA16(a[mt], bf, acc[j][mt]);
      }
    }
    #pragma unroll
    for (int j = 0; j < 2; ++j) {
      int j768 = (w + 8 * (pass * 2 + j)) * 16 + l15;
      int h = j768 / 96, j96 = j768 - h * 96;
      int which = j96 >> 5, d = j96 & 31;
      float bv = qkv_b[layer * 768 + which * 256 + h * 32 + d];
      float sc = (which == 0) ? 0.17677669529663687f : 1.0f;
      unsigned short* dst = qkvbuf + (((size_t)(b - b0) * 8 + h) * 3 + which) * 2304 + d;
      #pragma unroll
      for (int mt = 0; mt < 5; ++mt) {
        #pragma unroll
        for (int r = 0; r < 4; ++r) {
          int tok = mt * 16 + q4 * 4 + r;
          if (tok < NTOK) dst[tok * 32] = f2bf((acc[j][mt][r] + bv) * sc);
        }
      }
    }
  }
}

// ---------------- K3: attention per (sequence, head) ---------------------
#define SP_S 104
__global__ __launch_bounds__(256, 4)
void k_attn(const unsigned short* __restrict__ qkvbuf, unsigned short* __restrict__ ohbuf,
            int b0)
{
  __shared__ __align__(16) unsigned short qs[80 * 40];
  __shared__ __align__(16) unsigned short ks[80 * 40];
  __shared__ __align__(16) unsigned short vt[32 * 104];
  __shared__ __align__(16) unsigned short sp[80 * SP_S];
  const int tid = threadIdx.x, w = tid >> 6, l = tid & 63, q4 = l >> 4, l15 = l & 15;
  const int bh = blockIdx.x;
  const int b = (bh >> 3) + b0, h = bh & 7;
  const unsigned short* qg = qkvbuf + (size_t)bh * 6912;

  // zero only pad regions (disjoint from staged writes -> same phase is safe)
  for (int i = tid; i < 160; i += 256) {                  // qs/ks rows 72..79
    ((unsigned int*)(qs + 72 * 40))[i & 0x7fffffff] = 0u; // 8*40/2=160 words
  }
  for (int i = tid; i < 160; i += 256) ((unsigned int*)(ks + 72 * 40))[i] = 0u;
  for (int i = tid; i < 512; i += 256) {                  // vt cols 72..103 (32 rows x 16 words)
    int d = i >> 4, c = (i & 15) << 1;
    *(unsigned int*)(vt + d * 104 + 72 + c) = 0u;
  }
  for (int i = tid; i < 960; i += 256) {                  // sp cols 80..103 (80 rows x 12 words)
    int rr = i / 12, c = (i % 12) << 1;
    *(unsigned int*)(sp + rr * SP_S + 80 + c) = 0u;
  }
  // stage q, k, v(transposed)
  for (int i = tid; i < 288; i += 256) {
    int n = i >> 2, d8 = (i & 3) << 3;
    *(s8v*)(qs + n * 40 + d8) = *(const s8v*)(qg + n * 32 + d8);
  }
  for (int i = tid; i < 288; i += 256) {
    int n = i >> 2, d8 = (i & 3) << 3;
    *(s8v*)(ks + n * 40 + d8) = *(const s8v*)(qg + 2304 + n * 32 + d8);
  }
  for (int i = tid; i < 2304; i += 256) {
    int n = i >> 5, d = i & 31;
    vt[d * 104 + n] = qg[4608 + i];
  }
  __syncthreads();

  // scores (q pre-scaled in K2): sp[m][n2] bf16
  for (int t = w; t < 25; t += 4) {
    int mt = t / 5, kt = t - mt * 5;
    s8v a  = *(const s8v*)(qs + (mt * 16 + l15) * 40 + q4 * 8);
    s8v bf = *(const s8v*)(ks + (kt * 16 + l15) * 40 + q4 * 8);
    f4v c = MFMA16(a, bf, ((f4v){0, 0, 0, 0}));
    int rowb = mt * 16 + q4 * 4, col = kt * 16 + l15;
    #pragma unroll
    for (int r = 0; r < 4; ++r) sp[(rowb + r) * SP_S + col] = f2bf(c[r]);
  }
  __syncthreads();

  // exact top-20 on bf16 keys (16-bit radix) + softmax; P overwrites scores in-place
  for (int rp = 0; rp < 3; ++rp) {
    int row = rp * 32 + w * 8 + (l >> 3);
    if (row < NTOK) {
      int sub = l & 7;
      float vf[9]; unsigned int key[9];
      #pragma unroll
      for (int i = 0; i < 9; ++i) {
        unsigned int s = sp[row * SP_S + sub * 9 + i];
        vf[i] = bf2f((unsigned short)s);
        unsigned int m = (s >> 15) ? 0xFFFFu : 0x8000u;
        key[i] = s ^ m;
      }
      unsigned int thr = 0u;
      for (int bit = 15; bit >= 0; --bit) {
        unsigned int cand = thr | (1u << bit);
        int cnt = 0;
        #pragma unroll
        for (int i = 0; i < 9; ++i) cnt += (key[i] >= cand) ? 1 : 0;
        cnt += __shfl_xor(cnt, 1);
        cnt += __shfl_xor(cnt, 2);
        cnt += __shfl_xor(cnt, 4);
        if (cnt >= TOPM) thr = cand;
      }
      float mx = vf[0];
      #pragma unroll
      for (int i = 1; i < 9; ++i) mx = fmaxf(mx, vf[i]);
      mx = fmaxf(mx, __shfl_xor(mx, 1));
      mx = fmaxf(mx, __shfl_xor(mx, 2));
      mx = fmaxf(mx, __shfl_xor(mx, 4));
      float ssum = 0.f;
      #pragma unroll
      for (int i = 0; i < 9; ++i) {
        float e = (key[i] >= thr) ? __expf(vf[i] - mx) : 0.f;
        vf[i] = e; ssum += e;
      }
      ssum += __shfl_xor(ssum, 1);
      ssum += __shfl_xor(ssum, 2);
      ssum += __shfl_xor(ssum, 4);
      float inv = 1.f / ssum;
      #pragma unroll
      for (int i = 0; i < 9; ++i) sp[row * SP_S + sub * 9 + i] = f2bf(vf[i] * inv);
    }
  }
  __syncthreads();

  // out_h = P V  (K=96; pads zero)
  for (int t = w; t < 10; t += 4) {
    int mt = t >> 1, dt = t & 1;
    f4v acc = (f4v){0, 0, 0, 0};
    #pragma unroll
    for (int kk = 0; kk < 3; ++kk) {
      int k0 = kk * 32 + q4 * 8;
      s8v a  = *(const s8v*)(sp + (mt * 16 + l15) * SP_S + k0);
      s8v bf = *(const s8v*)(vt + (dt * 16 + l15) * 104 + k0);
      acc = MFMA16(a, bf, acc);
    }
    int rowb = mt * 16 + q4 * 4, d = dt * 16 + l15;
    unsigned short* dst = ohbuf + (size_t)b * 18432 + h * 32 + d;
    #pragma unroll
    for (int r = 0; r < 4; ++r) {
      int tok = rowb + r;
      if (tok < NTOK) dst[tok * 256] = f2bf(acc[r]);
    }
  }
}

// ---------------- K4: proj + residual + LN (+ classifier on last) --------
__global__ __launch_bounds__(512, 4)
void k_proj(const unsigned short* __restrict__ ohbuf, const unsigned short* __restrict__ wp,
            const float* __restrict__ proj_b, const float* __restrict__ ln_g,
            const float* __restrict__ ln_b,
            unsigned short* __restrict__ xb,
            const float* __restrict__ w1, const float* __restrict__ b1,
            const float* __restrict__ w2, const float* __restrict__ b2,
            float* __restrict__ out, int layer, int last)
{
  __shared__ __align__(16) unsigned short os[80 * 264];
  __shared__ float red[160];
  __shared__ float mbuf[256];
  __shared__ float hraw[128];
  const int tid = threadIdx.x, w = tid >> 6, l = tid & 63, q4 = l >> 4, l15 = l & 15;
  const int b = blockIdx.x;

  for (int i = tid; i < 80 * 264 / 2; i += 512) ((unsigned int*)os)[i] = 0u;
  if (tid < 160) red[tid] = 0.f;
  if (tid < 256) mbuf[tid] = 0.f;
  if (tid < 128) hraw[tid] = 0.f;
  __syncthreads();
  const unsigned short* ohb = ohbuf + (size_t)b * 18432;
  for (int i = tid; i < 2304; i += 512) {
    int n = i >> 5, c8 = (i & 31) << 3;
    *(s8v*)(os + n * 264 + c8) = *(const s8v*)(ohb + n * 256 + c8);
  }
  __syncthreads();

  const unsigned short* wpB = wp + (size_t)layer * 65536;
  f4v acc[5][2];
  #pragma unroll
  for (int mt = 0; mt < 5; ++mt) { acc[mt][0] = (f4v){0,0,0,0}; acc[mt][1] = (f4v){0,0,0,0}; }
  for (int kk = 0; kk < 8; ++kk) {
    int k0 = kk * 32 + q4 * 8;
    s8v a[5];
    #pragma unroll
    for (int mt = 0; mt < 5; ++mt) a[mt] = *(const s8v*)(os + (mt * 16 + l15) * 264 + k0);
    #pragma unroll
    for (int j = 0; j < 2; ++j) {
      int nrow = w * 32 + j * 16 + l15;
      s8v bf = *(const s8v*)(wpB + nrow * 256 + k0);
      #pragma unroll
      for (int mt = 0; mt < 5; ++mt) acc[mt][j] = MFMA16(a[mt], bf, acc[mt][j]);
    }
  }

  int c0 = w * 32 + l15, c1 = c0 + 16;
  float pb0 = proj_b[layer * 256 + c0], pb1 = proj_b[layer * 256 + c1];
  const unsigned short* xbb = xb + (size_t)b * 18432;
  #pragma unroll
  for (int mt = 0; mt < 5; ++mt) {
    #pragma unroll
    for (int r = 0; r < 4; ++r) {
      int row = mt * 16 + q4 * 4 + r;
      float z0 = 0.f, z1 = 0.f;
      if (row < NTOK) {
        z0 = bf2f(xbb[row * 256 + c0]) + acc[mt][0][r] + pb0;
        z1 = bf2f(xbb[row * 256 + c1]) + acc[mt][1][r] + pb1;
      }
      acc[mt][0][r] = z0; acc[mt][1][r] = z1;
      float s1 = z0 + z1, s2 = z0 * z0 + z1 * z1;
      s1 += __shfl_xor(s1, 1); s2 += __shfl_xor(s2, 1);
      s1 += __shfl_xor(s1, 2); s2 += __shfl_xor(s2, 2);
      s1 += __shfl_xor(s1, 4); s2 += __shfl_xor(s2, 4);
      s1 += __shfl_xor(s1, 8); s2 += __shfl_xor(s2, 8);
      if (l15 == 0 && row < NTOK) {
        atomicAdd(&red[row * 2], s1);
        atomicAdd(&red[row * 2 + 1], s2);
      }
    }
  }
  __syncthreads();

  float g0 = ln_g[layer * 256 + c0], g1 = ln_g[layer * 256 + c1];
  float be0 = ln_b[layer * 256 + c0], be1 = ln_b[layer * 256 + c1];
  unsigned short* xbw = xb + (size_t)b * 18432;
  float msum0 = 0.f, msum1 = 0.f;
  #pragma unroll
  for (int mt = 0; mt < 5; ++mt) {
    #pragma unroll
    for (int r = 0; r < 4; ++r) {
      int row = mt * 16 + q4 * 4 + r;
      if (row < NTOK) {
        float mu = red[row * 2] * (1.f / 256.f);
        float var = red[row * 2 + 1] * (1.f / 256.f) - mu * mu;
        float rstd = rsqrtf(var + 1e-5f);
        float o0 = (acc[mt][0][r] - mu) * rstd * g0 + be0;
        float o1 = (acc[mt][1][r] - mu) * rstd * g1 + be1;
        if (!last) {
          xbw[row * 256 + c0] = f2bf(o0);
          xbw[row * 256 + c1] = f2bf(o1);
        } else {
          msum0 += o0; msum1 += o1;
        }
      }
    }
  }
  if (last) {
    atomicAdd(&mbuf[c0], msum0);
    atomicAdd(&mbuf[c1], msum1);
    __syncthreads();
    if (tid < 256) mbuf[tid] *= (1.f / 72.f);
    __syncthreads();
    {  // h = mean @ W1: 512 threads = 128 cols x 4 k-quarters
      int col = tid & 127, kq = tid >> 7;
      float s = 0.f;
      for (int k = kq * 64; k < kq * 64 + 64; ++k) s += mbuf[k] * w1[k * 128 + col];
      atomicAdd(&hraw[col], s);
    }
    __syncthreads();
    if (w == 0) {
      float h0 = fmaxf(hraw[l] + b1[l], 0.f);
      float h1 = fmaxf(hraw[l + 64] + b1[l + 64], 0.f);
      float p = h0 * w2[l] + h1 * w2[l + 64];
      p += __shfl_xor(p, 1);  p += __shfl_xor(p, 2);  p += __shfl_xor(p, 4);
      p += __shfl_xor(p, 8);  p += __shfl_xor(p, 16); p += __shfl_xor(p, 32);
      if (l == 0) out[b] = p + b2[0];
    }
  }
}

extern "C" void kernel_launch(void* const* d_in, const int* in_sizes, int n_in,
                              void* d_out, int out_size, void* d_ws, size_t ws_size,
                              hipStream_t stream) {
  const float* rf    = (const float*)d_in[0];
  const float* pos   = (const float*)d_in[1];
  const float* qkvw  = (const float*)d_in[2];
  const float* qkvb  = (const float*)d_in[3];
  const float* projw = (const float*)d_in[4];
  const float* projb = (const float*)d_in[5];
  const float* lng   = (const float*)d_in[6];
  const float* lnb   = (const float*)d_in[7];
  const float* w1    = (const float*)d_in[8];
  const float* b1    = (const float*)d_in[9];
  const float* w2    = (const float*)d_in[10];
  const float* b2    = (const float*)d_in[11];
  float* out = (float*)d_out;

  // ws partition (u16 elements)
  unsigned short* wq  = (unsigned short*)d_ws;          // 2*768*256   = 393216
  unsigned short* wp  = wq + 393216;                    // 2*256*256   = 131072
  unsigned short* xb  = wp + 131072;                    // 1920*72*256 = 35389440
  unsigned short* oh  = xb + 35389440;                  // 1920*72*256 = 35389440
  unsigned short* qkv = oh + 35389440;                  // up to 1920*8*3*2304

  const size_t fixed_bytes = (size_t)(393216 + 131072 + 35389440 + 35389440) * 2;
  const size_t qkv_bytes   = (size_t)1920 * 8 * 3 * 2304 * 2;
  int nc = 1;
  while (nc < 8 && fixed_bytes + qkv_bytes / nc > ws_size) nc *= 2;
  const int bc = 1920 / nc;

  hipLaunchKernelGGL(pack_w, dim3(1536), dim3(256), 0, stream, qkvw, projw, wq, wp);
  for (int layer = 0; layer < 2; ++layer) {
    for (int c = 0; c < nc; ++c) {
      int b0 = c * bc;
      hipLaunchKernelGGL(k_qkv, dim3(bc), dim3(512), 0, stream,
                         rf, pos, xb, wq, qkvb, qkv, layer, b0);
      hipLaunchKernelGGL(k_attn, dim3(bc * 8), dim3(256), 0, stream, qkv, oh, b0);
    }
    hipLaunchKernelGGL(k_proj, dim3(1920), dim3(512), 0, stream,
                       oh, wp, projb, lng, lnb, xb, w1, b1, w2, b2, out,
                       layer, layer == 1 ? 1 : 0);
  }
}